// Round 8
// baseline (122.211 us; speedup 1.0000x reference)
//
#include <hip/hip_runtime.h>
#include <hip/hip_bf16.h>

#define EE 256
#define HIDD 150
#define HP 160
#define NN 384
#define NB 2
#define NJT 6
#define RPB 4
#define XJS 264   // XJ row stride (halfs): 132 dw = 4 mod 32 bank walk
#define HTS2 168  // Ht row stride (halfs): 84 dw = 20 mod 32, period-8 bank walk

typedef float f32x4 __attribute__((ext_vector_type(4)));
typedef _Float16 half8 __attribute__((ext_vector_type(8)));
typedef _Float16 half4 __attribute__((ext_vector_type(4)));

// ---- merged prep: blocks 0..259 pack weights; blocks 260..451 compute U/V/Xh ----
// frag k-convention: index=lane&15, k=(lane>>4)*8+e (within each 32-K step)
__global__ void prep(const float* __restrict__ W1, const float* __restrict__ W2,
                     const float* __restrict__ b2, const float* __restrict__ X,
                     const float* __restrict__ b1,
                     _Float16* __restrict__ w1p, _Float16* __restrict__ w2p,
                     _Float16* __restrict__ Xh, float* __restrict__ U,
                     float* __restrict__ V) {
  __shared__ float xs[RPB][EE];
  int blk = blockIdx.x;
  int tid = threadIdx.x;
  if (blk < 260) {
    int idx = blk * 256 + tid;
    if (idx < 40960) {
      int e = idx & 7, lane = (idx >> 3) & 63, tile = idx >> 9;
      int t = tile % 10, k8 = tile / 10;
      int eg = k8 * 32 + ((lane >> 4) << 3) + e;
      int h = t * 16 + (lane & 15);
      w1p[idx] = (_Float16)((h < HIDD) ? W1[(512 + eg) * HIDD + h] : 0.f);
    }
    int idx2 = idx - 40960;
    if (idx2 >= 0 && idx2 < 25600) {
      int e = idx2 & 7, lane = (idx2 >> 3) & 63, tile = idx2 >> 9;
      int t = tile % 10, k5 = tile / 10;
      int kk = k5 * 32 + ((lane >> 4) << 3) + e;
      int h = t * 16 + (lane & 15);
      float v = 0.f;
      if (h < HIDD) {
        if (kk < HIDD) v = W2[kk * HIDD + h];
        else if (kk == HIDD) v = b2[h];  // b2 folded: h1[.][150] forced to 1.0 in main
      }
      w2p[idx2] = (_Float16)v;
    }
  } else {
    int r0 = (blk - 260) * RPB;
    for (int q = tid; q < RPB * EE; q += 256) {
      float xv = X[r0 * EE + q];
      xs[q >> 8][q & 255] = xv;
      Xh[r0 * EE + q] = (_Float16)xv;
    }
    __syncthreads();
    int h = tid;
    if (h < HP) {
      float u[RPB] = {0, 0, 0, 0}, v[RPB] = {0, 0, 0, 0};
      if (h < HIDD) {
        for (int e = 0; e < EE; e++) {
          float wa = W1[e * HIDD + h];
          float wb = W1[(EE + e) * HIDD + h];
          #pragma unroll
          for (int r = 0; r < RPB; r++) {
            u[r] = fmaf(xs[r][e], wa, u[r]);
            v[r] = fmaf(xs[r][e], wb, v[r]);
          }
        }
        float bb = b1[h];
        #pragma unroll
        for (int r = 0; r < RPB; r++) u[r] += bb;
      }
      #pragma unroll
      for (int r = 0; r < RPB; r++) {
        U[(r0 + r) * HP + h] = u[r];
        V[(r0 + r) * HP + h] = v[r];
      }
    }
  }
}

// ---- main: block = (b, i-pair, j-tile 64); 10 waves; wave w OWNS h-tile t=w ----
// Weights live in REGISTERS (W1c: 8 frags, W2: 5 frags per wave). No streaming,
// no DMA, 3 barriers per block. A-operand (xi.xj) built from LDS-staged XJ tile.
__global__ __launch_bounds__(640) void pair_main(
    const _Float16* __restrict__ Xh, const float* __restrict__ M,
    const float* __restrict__ W3, const float* __restrict__ b3,
    const float* __restrict__ U, const float* __restrict__ V,
    const _Float16* __restrict__ w1p, const _Float16* __restrict__ w2p,
    float* __restrict__ out) {
  int bx = blockIdx.x;
  int jt = bx % NJT;
  int ig = (bx / NJT) % (NN / 2);
  int b = bx / (NJT * (NN / 2));
  int i0 = ig * 2;

  int tid = threadIdx.x;
  int lane = tid & 63;
  int w = tid >> 6;        // 0..9: owned t-tile (h = w*16 .. w*16+15)
  int hcol = lane & 15;
  int rgrp = lane >> 4;

  __shared__ __align__(16) _Float16 XJ[64 * XJS];       // 33.8 KB, j-tile of Xh
  __shared__ __align__(16) _Float16 Ht[2][64 * HTS2];   // 42 KB, h1 fp16
  __shared__ __align__(16) _Float16 xsl[2 * EE];        // 1 KB, the 2 i-rows
  __shared__ float ms[64];
  float* partials = reinterpret_cast<float*>(&XJ[0]);   // [10][2][64] f32, aliases XJ (dead after GEMM1)

  // ---- stage XJ (64 j-rows x 256), xsl, ms ----
  for (int q = tid; q < 64 * 32; q += 640) {
    int r = q >> 5, c = (q & 31) << 3;
    *reinterpret_cast<half8*>(&XJ[r * XJS + c]) =
        *reinterpret_cast<const half8*>(Xh + (size_t)(b * NN + jt * 64 + r) * EE + c);
  }
  if (tid < 64) {
    int r = tid >> 5, c = (tid & 31) << 3;
    *reinterpret_cast<half8*>(&xsl[r * EE + c]) =
        *reinterpret_cast<const half8*>(Xh + (size_t)(b * NN + i0 + r) * EE + c);
    ms[tid] = M[b * NN + jt * 64 + tid];
  }

  // ---- resident W1c fragments for this wave's t-slice (8 x half8 = 32 VGPR) ----
  half8 w1f[8];
  #pragma unroll
  for (int k8 = 0; k8 < 8; k8++)
    w1f[k8] = *reinterpret_cast<const half8*>(w1p + (k8 * 10 + w) * 512 + lane * 8);

  // ---- acc init: U[i,h] + V[j,h] (h = w*16 + rgrp*4 + r) ----
  int hb = w * 16 + rgrp * 4;
  f32x4 acc[2][4];
  {
    float4 u0 = *reinterpret_cast<const float4*>(U + (size_t)(b * NN + i0) * HP + hb);
    float4 u1 = *reinterpret_cast<const float4*>(U + (size_t)(b * NN + i0 + 1) * HP + hb);
    #pragma unroll
    for (int jf = 0; jf < 4; jf++) {
      float4 v4 = *reinterpret_cast<const float4*>(
          V + (size_t)(b * NN + jt * 64 + jf * 16 + hcol) * HP + hb);
      acc[0][jf][0] = u0.x + v4.x; acc[0][jf][1] = u0.y + v4.y;
      acc[0][jf][2] = u0.z + v4.z; acc[0][jf][3] = u0.w + v4.w;
      acc[1][jf][0] = u1.x + v4.x; acc[1][jf][1] = u1.y + v4.y;
      acc[1][jf][2] = u1.z + v4.z; acc[1][jf][3] = u1.w + v4.w;
    }
  }

  __syncthreads();  // barrier 1: XJ/xsl visible

  // ---- GEMM1: C1^T[h(own t), j] += W1c^T (xi.xj), all K in registers/LDS ----
  #pragma unroll
  for (int k8 = 0; k8 < 8; k8++) {
    half8 xi0 = *reinterpret_cast<const half8*>(&xsl[k8 * 32 + rgrp * 8]);
    half8 xi1 = *reinterpret_cast<const half8*>(&xsl[EE + k8 * 32 + rgrp * 8]);
    #pragma unroll
    for (int jf = 0; jf < 4; jf++) {
      half8 xj = *reinterpret_cast<const half8*>(
          &XJ[(jf * 16 + hcol) * XJS + k8 * 32 + rgrp * 8]);
      acc[0][jf] = __builtin_amdgcn_mfma_f32_16x16x32_f16(w1f[k8], xi0 * xj, acc[0][jf], 0, 0, 0);
      acc[1][jf] = __builtin_amdgcn_mfma_f32_16x16x32_f16(w1f[k8], xi1 * xj, acc[1][jf], 0, 0, 0);
    }
  }

  // ---- relu -> fp16 -> Ht[i][j][h]; wave 9/rgrp1 sets h=150 to 1.0 (b2 via W2 k-row) ----
  #pragma unroll
  for (int i = 0; i < 2; i++) {
    #pragma unroll
    for (int jf = 0; jf < 4; jf++) {
      half4 hv;
      hv[0] = (_Float16)fmaxf(acc[i][jf][0], 0.f);
      hv[1] = (_Float16)fmaxf(acc[i][jf][1], 0.f);
      hv[2] = (_Float16)fmaxf(acc[i][jf][2], 0.f);
      hv[3] = (_Float16)fmaxf(acc[i][jf][3], 0.f);
      if (w == 9 && rgrp == 1) hv[2] = (_Float16)1.0f;  // h = 144+4+2 = 150
      *reinterpret_cast<half4*>(&Ht[i][(jf * 16 + hcol) * HTS2 + hb]) = hv;
    }
  }

  // ---- resident W2 fragments (loaded late: keeps GEMM1 VGPR peak low) ----
  half8 w2f[5];
  #pragma unroll
  for (int k5 = 0; k5 < 5; k5++)
    w2f[k5] = *reinterpret_cast<const half8*>(w2p + (k5 * 10 + w) * 512 + lane * 8);

  __syncthreads();  // barrier 2: Ht complete

  // ---- GEMM2: D2[j, h2(own t)] = Ht x W2 ----
  f32x4 acc2[2][4];
  #pragma unroll
  for (int i = 0; i < 2; i++)
    #pragma unroll
    for (int jf = 0; jf < 4; jf++) {
      acc2[i][jf][0] = 0.f; acc2[i][jf][1] = 0.f;
      acc2[i][jf][2] = 0.f; acc2[i][jf][3] = 0.f;
    }
  #pragma unroll
  for (int k5 = 0; k5 < 5; k5++) {
    #pragma unroll
    for (int i = 0; i < 2; i++) {
      #pragma unroll
      for (int jf = 0; jf < 4; jf++) {
        half8 a = *reinterpret_cast<const half8*>(
            &Ht[i][(jf * 16 + hcol) * HTS2 + k5 * 32 + rgrp * 8]);
        acc2[i][jf] = __builtin_amdgcn_mfma_f32_16x16x32_f16(a, w2f[k5], acc2[i][jf], 0, 0, 0);
      }
    }
  }

  // ---- layer 3 partials: sum over own 16 h2 via W3, reduce across hcol lanes ----
  int h2 = w * 16 + hcol;
  float w3 = (h2 < HIDD) ? W3[h2] : 0.f;
  #pragma unroll
  for (int i = 0; i < 2; i++) {
    #pragma unroll
    for (int jf = 0; jf < 4; jf++) {
      float p0 = fmaxf(acc2[i][jf][0], 0.f) * w3;
      float p1 = fmaxf(acc2[i][jf][1], 0.f) * w3;
      float p2 = fmaxf(acc2[i][jf][2], 0.f) * w3;
      float p3 = fmaxf(acc2[i][jf][3], 0.f) * w3;
      #pragma unroll
      for (int mk = 1; mk <= 8; mk <<= 1) {
        p0 += __shfl_xor(p0, mk);
        p1 += __shfl_xor(p1, mk);
        p2 += __shfl_xor(p2, mk);
        p3 += __shfl_xor(p3, mk);
      }
      if (hcol == 0) {
        float4 pv = {p0, p1, p2, p3};
        *reinterpret_cast<float4*>(
            &partials[(w * 2 + i) * 64 + jf * 16 + rgrp * 4]) = pv;
      }
    }
  }

  __syncthreads();  // barrier 3: partials complete

  if (tid < 128) {
    int i = tid >> 6, j = tid & 63;
    float s = 0.f;
    #pragma unroll
    for (int ww = 0; ww < 10; ww++) s += partials[(ww * 2 + i) * 64 + j];
    float o = (M[b * NN + i0 + i] + ms[j] + s + b3[0]) * (1.f / 3.f);
    out[(size_t)(b * NN + i0 + i) * NN + jt * 64 + j] = o;
  }
}

extern "C" void kernel_launch(void* const* d_in, const int* in_sizes, int n_in,
                              void* d_out, int out_size, void* d_ws, size_t ws_size,
                              hipStream_t stream) {
  const float* X  = (const float*)d_in[0];
  const float* M  = (const float*)d_in[1];
  const float* W1 = (const float*)d_in[2];
  const float* b1 = (const float*)d_in[3];
  const float* W2 = (const float*)d_in[4];
  const float* b2 = (const float*)d_in[5];
  const float* W3 = (const float*)d_in[6];
  const float* b3 = (const float*)d_in[7];
  float* out = (float*)d_out;

  float* U  = (float*)d_ws;                        // 768*160 f32
  float* V  = U + NB * NN * HP;                    // 768*160 f32
  _Float16* Xh  = (_Float16*)(V + NB * NN * HP);   // 768*256 f16
  _Float16* w1p = Xh + NB * NN * EE;               // 40960 f16
  _Float16* w2p = w1p + 40960;                     // 25600 f16

  hipLaunchKernelGGL(prep, dim3(452), dim3(256), 0, stream,
                     W1, W2, b2, X, b1, w1p, w2p, Xh, U, V);
  hipLaunchKernelGGL(pair_main, dim3(NB * (NN / 2) * NJT), dim3(640), 0, stream,
                     Xh, M, W3, b3, U, V, w1p, w2p, out);
}